// Round 1
// baseline (75.437 us; speedup 1.0000x reference)
//
#include <hip/hip_runtime.h>
#include <hip/hip_bf16.h>

// Leave-one-out Gaussian-kernel regression (Nadaraya-Watson), N=4096, D_IN=4, D_OUT=3.
// out[i,c] = (sum_{j!=i} K_jic * Y[j,c]) / (sum_{j!=i} K_jic)
// K_jic = exp(-0.5*((Ft[j,c]-Fx[i,c])/h)^2),  Fx = x@W^T, Ft = train_X@W^T.
//
// Single fused kernel. Algebra: with s = -log2(e)/(2h^2),
//   K = 2^{s(ft-fx)^2} = 2^{s·ft^2} · 2^{-2s·ft·fx} · 2^{s·fx^2}.
// The last factor depends only on (i,c) => cancels in num/den. So accumulate
//   K' = 2^{ fma(w2, ft, A) },  A = (s·ft)·ft (per j),  w2 = -2s·fx (per i).
// Inner eval = 1 fma + 1 exp2 + 1 add + 1 fma = 3 VALU + 1 transcendental.
//
// R1 change (occupancy): TI 8 -> 4. Grid 1024 blocks x 256 thr = 4096 waves
// = 4 waves/SIMD (was 2). The prior 77 us at ~46 cyc/issued-instr is a
// latency signature, not throughput (throughput floor ~3 us) -- more resident
// waves is the lever. TI=4 also halves accumulator VGPRs (unroll 2->4 now
// affordable) and halves the butterfly epilogue (144 shuffles).
// Self-term subtracted analytically in the epilogue (recomputed from globals
// -- NO dynamic register-array indexing; that caused a scratch regression).

constexpr int BLK = 256;  // threads per block (4 waves)
constexpr int TI  = 4;    // query points per block

__global__ __launch_bounds__(BLK) void kde_fused(const float* __restrict__ x,
                                                 const float* __restrict__ tX,
                                                 const float* __restrict__ Y,
                                                 const float* __restrict__ W,
                                                 const float* __restrict__ hptr,
                                                 float* __restrict__ out, int N) {
    const int i0  = blockIdx.x * TI;
    const int tid = threadIdx.x;

    const float h = hptr[0];
    const float scale = -0.72134752044448170368f / (h * h);  // -log2(e)/(2h^2)

    // W is 12 wave-uniform floats -> scalar loads
    float w[12];
#pragma unroll
    for (int k = 0; k < 12; ++k) w[k] = W[k];

    // Per-query constants w2[a][c] = -2*scale*fx  (all static indexing)
    float w2[TI][3];
#pragma unroll
    for (int a = 0; a < TI; ++a) {
        float4 xv = ((const float4*)x)[i0 + a];
#pragma unroll
        for (int c = 0; c < 3; ++c) {
            float fx = fmaf(xv.x, w[4 * c + 0],
                       fmaf(xv.y, w[4 * c + 1],
                       fmaf(xv.z, w[4 * c + 2], xv.w * w[4 * c + 3])));
            w2[a][c] = -2.f * scale * fx;
        }
    }

    float num[TI][3], den[TI][3];
#pragma unroll
    for (int a = 0; a < TI; ++a)
#pragma unroll
        for (int c = 0; c < 3; ++c) { num[a][c] = 0.f; den[a][c] = 0.f; }

#pragma unroll 4
    for (int j = tid; j < N; j += BLK) {
        float4 tv = ((const float4*)tX)[j];
        float yv[3];
        yv[0] = Y[3 * j + 0]; yv[1] = Y[3 * j + 1]; yv[2] = Y[3 * j + 2];
        float ft[3], A[3];
#pragma unroll
        for (int c = 0; c < 3; ++c) {
            ft[c] = fmaf(tv.x, w[4 * c + 0],
                    fmaf(tv.y, w[4 * c + 1],
                    fmaf(tv.z, w[4 * c + 2], tv.w * w[4 * c + 3])));
            float v = scale * ft[c];
            A[c] = v * ft[c];
        }
#pragma unroll
        for (int a = 0; a < TI; ++a)
#pragma unroll
            for (int c = 0; c < 3; ++c) {
                float arg = fmaf(w2[a][c], ft[c], A[c]);
                float k   = __builtin_amdgcn_exp2f(arg);
                den[a][c] += k;
                num[a][c]  = fmaf(k, yv[c], num[a][c]);
            }
    }

    // 64-lane wave butterfly, then 4-wave LDS combine
    __shared__ float s_n[4][TI * 3];
    __shared__ float s_d[4][TI * 3];
    const int lane = tid & 63, wave = tid >> 6;
#pragma unroll
    for (int a = 0; a < TI; ++a)
#pragma unroll
        for (int c = 0; c < 3; ++c) {
            float n_ = num[a][c], d_ = den[a][c];
#pragma unroll
            for (int off = 32; off > 0; off >>= 1) {
                n_ += __shfl_down(n_, off, 64);
                d_ += __shfl_down(d_, off, 64);
            }
            if (lane == 0) { s_n[wave][a * 3 + c] = n_; s_d[wave][a * 3 + c] = d_; }
        }
    __syncthreads();

    if (tid < TI * 3) {
        const int a = tid / 3, c = tid - 3 * a;
        const int i = i0 + a;
        float n_ = s_n[0][tid] + s_n[1][tid] + s_n[2][tid] + s_n[3][tid];
        float d_ = s_d[0][tid] + s_d[1][tid] + s_d[2][tid] + s_d[3][tid];

        // Self-term (j==i), recomputed from globals with the SAME op order as
        // the main loop. Runtime c indexes GLOBAL W (VMEM), not a reg array.
        float4 xv = ((const float4*)x)[i];
        float fx = fmaf(xv.x, W[4 * c + 0],
                   fmaf(xv.y, W[4 * c + 1],
                   fmaf(xv.z, W[4 * c + 2], xv.w * W[4 * c + 3])));
        float w2v = -2.f * scale * fx;
        float4 tv = ((const float4*)tX)[i];
        float ft = fmaf(tv.x, W[4 * c + 0],
                   fmaf(tv.y, W[4 * c + 1],
                   fmaf(tv.z, W[4 * c + 2], tv.w * W[4 * c + 3])));
        float v  = scale * ft;
        float A  = v * ft;
        float kii = __builtin_amdgcn_exp2f(fmaf(w2v, ft, A));
        float yii = Y[3 * i + c];

        out[3 * i + c] = (n_ - kii * yii) / (d_ - kii);
    }
}

extern "C" void kernel_launch(void* const* d_in, const int* in_sizes, int n_in,
                              void* d_out, int out_size, void* d_ws, size_t ws_size,
                              hipStream_t stream) {
    const float* x  = (const float*)d_in[0];  // [N,4]
    const float* tX = (const float*)d_in[1];  // [N,4]
    const float* Y  = (const float*)d_in[2];  // [N,3]
    const float* W  = (const float*)d_in[3];  // [3,4]
    const float* h  = (const float*)d_in[4];  // [1]

    const int N = in_sizes[0] / 4;  // 4096

    kde_fused<<<N / TI, BLK, 0, stream>>>(x, tX, Y, W, h, (float*)d_out, N);
}